// Round 4
// baseline (77.375 us; speedup 1.0000x reference)
//
#include <hip/hip_runtime.h>
#include <hip/hip_bf16.h>
#include <hip/hip_cooperative_groups.h>
#include <math.h>

namespace cg = cooperative_groups;

// Problem constants
#define B 2048
#define F 26
#define C 64
#define E 64
#define D 13
#define SPARSE_W (F * (C + 1) - 1)   // 1689
#define K (F * C)                    // 1664
#define MT 16                        // samples per block
#define ROWW 836                     // dwords per LDS count row (3344 B)

typedef short short8 __attribute__((ext_vector_type(8)));
typedef float f32x4  __attribute__((ext_vector_type(4)));

#define WS_NEED ((size_t)K * 128 * 2)   // Bt: 425,984 B

// ---------------------------------------------------------------------------
// Single cooperative kernel:
//  phase P (blocks 0..25): transpose feature slab -> Bt[n][k] bf16 (n<64: emb,
//           n>=64: emb^2), overlapped with phase H on all blocks
//  phase H (all blocks): LDS u16 histogram of 16 samples + linear term
//  grid.sync()
//  phase G: MFMA GEMM 16 x 128 x 1664 (A=LDS counts, B=Bt) + pairwise epilogue
__global__ __launch_bounds__(512) void dfm_coop(
    const int*   __restrict__ sparse,
    const float* __restrict__ dense,
    const float* __restrict__ lin_emb,
    const float* __restrict__ emb_tab,
    const float* __restrict__ lin_W,
    const float* __restrict__ lin_b,
    __hip_bfloat16* __restrict__ bt,
    float* __restrict__ out)
{
    __shared__ unsigned int cnt[MT * ROWW];   // 53,504 B
    __shared__ float ftile[64][65];           // 16,640 B (prep blocks only)
    __shared__ float lin_lds[MT];
    __shared__ float pair_lds[MT];

    const int tid  = threadIdx.x;
    const int lane = tid & 63;
    const int w    = tid >> 6;          // wave 0..7
    const int b0   = blockIdx.x * MT;

    for (int i = tid; i < MT * ROWW; i += 512) cnt[i] = 0;
    if (tid < MT) pair_lds[tid] = 0.f;

    // ---- phase P: blocks 0..25 build Bt for feature f = blockIdx.x
    if (blockIdx.x < F) {
        const int f = blockIdx.x;
        const float* src = emb_tab + (size_t)f * 4096;   // [v][e]
        for (int i = tid; i < 4096; i += 512)
            ftile[i >> 6][i & 63] = src[i];
        __syncthreads();
        unsigned int* btw = (unsigned int*)bt;
        const int u  = tid & 31;         // dword: covers v = 2u, 2u+1
        const int n0 = tid >> 5;         // 0..15
        #pragma unroll
        for (int it = 0; it < 8; ++it) {
            const int n = n0 + it * 16;  // 0..127
            float lo = ftile[2 * u][n & 63];
            float hi = ftile[2 * u + 1][n & 63];
            if (n >= 64) { lo *= lo; hi *= hi; }
            __hip_bfloat16 l16 = __float2bfloat16(lo);
            __hip_bfloat16 h16 = __float2bfloat16(hi);
            unsigned int dw = ((unsigned int)*(unsigned short*)&h16 << 16)
                            |  (unsigned int)*(unsigned short*)&l16;
            btw[(size_t)n * (K / 2) + f * 32 + u] = dw;
        }
    }
    __syncthreads();   // cnt zeroing visible block-wide

    // ---- phase H: u16 histogram + linear term. wave w owns rows w, w+8.
    const int r0 = w, r1 = w + 8;
    const int* sp0 = sparse + (size_t)(b0 + r0) * SPARSE_W + lane;
    const int* sp1 = sparse + (size_t)(b0 + r1) * SPARSE_W + lane;
    int idx0[F], idx1[F];
    #pragma unroll
    for (int f = 0; f < F; ++f) idx0[f] = sp0[f * (C + 1)];
    #pragma unroll
    for (int f = 0; f < F; ++f) idx1[f] = sp1[f * (C + 1)];

    float lin0 = 0.f, lin1 = 0.f;
    #pragma unroll
    for (int f = 0; f < F; ++f) {
        const int k0 = f * 64 + idx0[f];
        const int k1 = f * 64 + idx1[f];
        atomicAdd(&cnt[r0 * ROWW + (k0 >> 1)], 1u << (16 * (k0 & 1)));
        atomicAdd(&cnt[r1 * ROWW + (k1 >> 1)], 1u << (16 * (k1 & 1)));
        lin0 = fmaf(lin_W[f], lin_emb[f * 64 + idx0[f]], lin0);
        lin1 = fmaf(lin_W[f], lin_emb[f * 64 + idx1[f]], lin1);
    }
    #pragma unroll
    for (int m = 32; m >= 1; m >>= 1) {
        lin0 += __shfl_xor(lin0, m);
        lin1 += __shfl_xor(lin1, m);
    }
    if (lane == 0) { lin_lds[r0] = lin0; lin_lds[r1] = lin1; }
    __syncthreads();

    // ---- convert u16 counts -> bf16 in place (ints <=64 exact)
    {
        const int row = tid >> 5;          // 16 rows x 32 threads
        const int cl  = tid & 31;
        unsigned int* rp = &cnt[row * ROWW];
        #pragma unroll
        for (int it = 0; it < 26; ++it) {  // 832 used dwords per row
            const int j = cl + it * 32;
            const unsigned int v = rp[j];
            const float flo = (float)(v & 0xffffu);
            const float fhi = (float)(v >> 16);
            rp[j] = (__float_as_uint(fhi) & 0xffff0000u) | (__float_as_uint(flo) >> 16);
        }
    }
    __syncthreads();

    // ---- make Bt writes visible device-wide, then grid barrier
    __threadfence();
    cg::this_grid().sync();

    // ---- phase G: GEMM 16 x 128 x 1664. A: LDS bf16 counts; B: Bt (L2).
    // wave w -> cols [16w, 16w+16). A-frag: row=l&15, k=(l>>4)*8+j (16B).
    f32x4 acc_a = {0.f, 0.f, 0.f, 0.f};
    f32x4 acc_b = {0.f, 0.f, 0.f, 0.f};
    const char*  abase = (const char*)cnt + (lane & 15) * (ROWW * 4) + (lane >> 4) * 16;
    const short* pb    = (const short*)bt + (size_t)(w * 16 + (lane & 15)) * K + (lane >> 4) * 8;
    #pragma unroll 4
    for (int kk = 0; kk < 52; kk += 2) {
        short8 a0  = *(const short8*)(abase + (size_t)kk * 64);
        short8 b0v = *(const short8*)(pb + (size_t)kk * 32);
        short8 a1  = *(const short8*)(abase + (size_t)(kk + 1) * 64);
        short8 b1v = *(const short8*)(pb + (size_t)(kk + 1) * 32);
        acc_a = __builtin_amdgcn_mfma_f32_16x16x32_bf16(a0, b0v, acc_a, 0, 0, 0);
        acc_b = __builtin_amdgcn_mfma_f32_16x16x32_bf16(a1, b1v, acc_b, 0, 0, 0);
    }

    // ---- epilogue: pair[row] += sum_cols (S^2) and (-SQ)
    #pragma unroll
    for (int r = 0; r < 4; ++r) {
        const float v = acc_a[r] + acc_b[r];
        float c = (w < 4) ? v * v : -v;
        c += __shfl_xor(c, 1);
        c += __shfl_xor(c, 2);
        c += __shfl_xor(c, 4);
        c += __shfl_xor(c, 8);
        if ((lane & 15) == 0)
            atomicAdd(&pair_lds[(lane >> 4) * 4 + r], c);
    }
    __syncthreads();

    if (tid < MT) {
        const int row = tid;
        float x = lin_lds[row] + lin_b[0] + 0.5f * pair_lds[row];
        const float* dp = dense + (size_t)(b0 + row) * D;
        #pragma unroll
        for (int j = 0; j < D; ++j) x = fmaf(dp[j], lin_W[F + j], x);
        out[b0 + row] = 1.f / (1.f + expf(-x));
    }
}

// ---------------------------------------------------------------------------
// Fallback (round-1 kernel) if ws is too small.
__global__ __launch_bounds__(256) void dfm_fallback(
    const int*   __restrict__ sparse,
    const float* __restrict__ dense,
    const float* __restrict__ lin_emb,
    const float* __restrict__ emb_tab,
    const float* __restrict__ lin_W,
    const float* __restrict__ lin_b,
    float*       __restrict__ out)
{
    const int lane = threadIdx.x & 63;
    const int wv   = threadIdx.x >> 6;
    const int b    = blockIdx.x * 4 + wv;
    if (b >= B) return;
    const int g = lane >> 4;
    const int t = lane & 15;
    const float4* emb4 = reinterpret_cast<const float4*>(emb_tab);
    float4 s  = make_float4(0.f, 0.f, 0.f, 0.f);
    float4 sq = make_float4(0.f, 0.f, 0.f, 0.f);
    float  lin = 0.f;
    const int sbase = b * SPARSE_W;
    for (int f = 0; f < F; ++f) {
        int idxreg = sparse[sbase + f * (C + 1) + lane];
        lin = fmaf(lin_W[f], lin_emb[f * C + idxreg], lin);
        const float4* rowbase = emb4 + (size_t)(f * C) * 16 + t;
        #pragma unroll
        for (int cc = 0; cc < 16; ++cc) {
            const int c   = g * 16 + cc;
            const int idx = __shfl(idxreg, c);
            float4 w = rowbase[idx * 16];
            s.x += w.x; s.y += w.y; s.z += w.z; s.w += w.w;
            sq.x = fmaf(w.x, w.x, sq.x);
            sq.y = fmaf(w.y, w.y, sq.y);
            sq.z = fmaf(w.z, w.z, sq.z);
            sq.w = fmaf(w.w, w.w, sq.w);
        }
    }
    if (lane < D) lin = fmaf(dense[b * D + lane], lin_W[F + lane], lin);
    #pragma unroll
    for (int m = 32; m >= 1; m >>= 1) lin += __shfl_xor(lin, m);
    #pragma unroll
    for (int m = 16; m <= 32; m <<= 1) {
        s.x += __shfl_xor(s.x, m); s.y += __shfl_xor(s.y, m);
        s.z += __shfl_xor(s.z, m); s.w += __shfl_xor(s.w, m);
    }
    float sql = sq.x + sq.y + sq.z + sq.w;
    #pragma unroll
    for (int m = 32; m >= 1; m >>= 1) sql += __shfl_xor(sql, m);
    float s2 = s.x * s.x + s.y * s.y + s.z * s.z + s.w * s.w;
    #pragma unroll
    for (int m = 8; m >= 1; m >>= 1) s2 += __shfl_xor(s2, m);
    if (lane == 0) {
        const float pair = 0.5f * (s2 - sql);
        const float x = lin + lin_b[0] + pair;
        out[b] = 1.f / (1.f + expf(-x));
    }
}

extern "C" void kernel_launch(void* const* d_in, const int* in_sizes, int n_in,
                              void* d_out, int out_size, void* d_ws, size_t ws_size,
                              hipStream_t stream) {
    const int*   sparse  = (const int*)  d_in[0];
    const float* dense   = (const float*)d_in[1];
    const float* lin_emb = (const float*)d_in[2];
    const float* emb_tab = (const float*)d_in[3];
    const float* lin_W   = (const float*)d_in[4];
    const float* lin_b   = (const float*)d_in[5];
    float* out = (float*)d_out;

    if (ws_size < WS_NEED) {
        dim3 grid((B + 3) / 4), block(256);
        hipLaunchKernelGGL(dfm_fallback, grid, block, 0, stream,
                           sparse, dense, lin_emb, emb_tab, lin_W, lin_b, out);
        return;
    }

    __hip_bfloat16* bt = (__hip_bfloat16*)d_ws;

    void* args[] = { (void*)&sparse, (void*)&dense, (void*)&lin_emb,
                     (void*)&emb_tab, (void*)&lin_W, (void*)&lin_b,
                     (void*)&bt, (void*)&out };
    hipLaunchCooperativeKernel((const void*)dfm_coop, dim3(B / MT), dim3(512),
                               args, 0, stream);
}

// Round 5
// 43.816 us; speedup vs baseline: 1.7659x; 1.7659x over previous
//
#include <hip/hip_runtime.h>
#include <hip/hip_bf16.h>
#include <math.h>

// Problem constants
#define B 2048
#define F 26
#define C 64
#define E 64
#define D 13
#define SPARSE_W (F * (C + 1) - 1)   // 1689
#define K (F * C)                    // 1664
#define KD (K / 2)                   // 832 dwords per count row

typedef short short8 __attribute__((ext_vector_type(8)));
typedef float f32x4  __attribute__((ext_vector_type(4)));

// ws layout (bytes)
#define CNT_OFF  0
#define BT_OFF   ((size_t)B * K * 2)                 // 6,815,744
#define LIN_OFF  (BT_OFF + (size_t)K * 128 * 2)      // +425,984
#define PAIR_OFF (LIN_OFF + (size_t)B * 4)
#define DONE_OFF (PAIR_OFF + (size_t)B * 4)
#define WS_NEED  (DONE_OFF + 128 * 4)

// ---------------------------------------------------------------------------
// K1: blocks [0,2048): per-sample LDS histogram -> bf16 count row + linear.
//     blocks [2048,2074): transpose/square emb_tab -> bt; zero pair/done.
__global__ __launch_bounds__(256) void hist_prep_kernel(
    const int*   __restrict__ sparse,
    const float* __restrict__ lin_emb,
    const float* __restrict__ emb_tab,
    const float* __restrict__ lin_W,
    __hip_bfloat16* __restrict__ cntg,
    __hip_bfloat16* __restrict__ bt,
    float* __restrict__ lin,
    float* __restrict__ pair,
    unsigned int* __restrict__ done)
{
    __shared__ union SM {
        struct { unsigned int row[KD]; float linp[4]; } h;
        float ftile[64][65];
    } sm;
    const int tid = threadIdx.x;

    if (blockIdx.x >= B) {
        // ---- prep path: one feature slab per block
        const int f = blockIdx.x - B;
        const int t = f * 256 + tid;
        if (t < B)   pair[t] = 0.f;
        if (t < 128) done[t] = 0u;

        const float* src = emb_tab + (size_t)f * 4096;   // [v][e]
        for (int i = tid; i < 4096; i += 256)
            sm.ftile[i >> 6][i & 63] = src[i];
        __syncthreads();
        unsigned int* btw = (unsigned int*)bt;
        const int u  = tid & 31;        // dword: v = 2u, 2u+1
        const int n0 = tid >> 5;        // 0..7
        #pragma unroll
        for (int it = 0; it < 16; ++it) {
            const int n = it * 8 + n0;  // 0..127
            float lo = sm.ftile[2 * u][n & 63];
            float hi = sm.ftile[2 * u + 1][n & 63];
            if (n >= 64) { lo *= lo; hi *= hi; }
            __hip_bfloat16 l16 = __float2bfloat16(lo);
            __hip_bfloat16 h16 = __float2bfloat16(hi);
            unsigned int dw = ((unsigned int)*(unsigned short*)&h16 << 16)
                            |  (unsigned int)*(unsigned short*)&l16;
            btw[(size_t)n * KD + f * 32 + u] = dw;
        }
        return;
    }

    // ---- hist path: one sample per block
    const int b = blockIdx.x;
    for (int i = tid; i < KD; i += 256) sm.h.row[i] = 0u;
    __syncthreads();

    const int* sp = sparse + (size_t)b * SPARSE_W;
    int vals[7];
    #pragma unroll
    for (int it = 0; it < 7; ++it) {
        const int p = tid + it * 256;
        vals[it] = (p < SPARSE_W) ? sp[p] : 0;
    }
    float linsum = 0.f;
    #pragma unroll
    for (int it = 0; it < 7; ++it) {
        const int p = tid + it * 256;
        if (p < SPARSE_W) {
            const int f = p / 65;
            const int c = p - f * 65;
            if (c < 64) {
                const int k = f * 64 + vals[it];
                atomicAdd(&sm.h.row[k >> 1], 1u << (16 * (k & 1)));
                linsum = fmaf(lin_W[f], lin_emb[f * 64 + vals[it]], linsum);
            }
        }
    }
    #pragma unroll
    for (int m = 32; m >= 1; m >>= 1) linsum += __shfl_xor(linsum, m);
    if ((tid & 63) == 0) sm.h.linp[tid >> 6] = linsum;
    __syncthreads();   // covers linp stores AND histogram atomics
    if (tid == 0)
        lin[b] = sm.h.linp[0] + sm.h.linp[1] + sm.h.linp[2] + sm.h.linp[3];

    // convert u16 -> bf16 (ints <=64 exact under truncation) + coalesced store
    unsigned int* cg = (unsigned int*)cntg + (size_t)b * KD;
    for (int i = tid; i < KD; i += 256) {
        const unsigned int v = sm.h.row[i];
        const float flo = (float)(v & 0xffffu);
        const float fhi = (float)(v >> 16);
        cg[i] = (__float_as_uint(fhi) & 0xffff0000u) | (__float_as_uint(flo) >> 16);
    }
}

// ---------------------------------------------------------------------------
// K2: one wave per 16x16 output tile, full K. 512 blocks x 128 thr.
// wid = lbid*2 + wave; mt = wid>>3 (128), nt = wid&7 (8).
// Chunked XCD swizzle: physical bids {x, x+8, ...} -> logical x*64..x*64+63,
// so each XCD owns 16 consecutive m-tiles (A-tiles L2-local, bt L2-resident).
__global__ __launch_bounds__(128) void gemm_kernel(
    const __hip_bfloat16* __restrict__ cnt,
    const __hip_bfloat16* __restrict__ bt,
    const float* __restrict__ dense,
    const float* __restrict__ lin_W,
    const float* __restrict__ lin_b,
    const float* __restrict__ lin,
    float* __restrict__ pair,
    unsigned int* __restrict__ done,
    float* __restrict__ out)
{
    const int bid  = blockIdx.x;
    const int lbid = (bid & 7) * 64 + (bid >> 3);
    const int wid  = lbid * 2 + (threadIdx.x >> 6);
    const int mt   = wid >> 3;
    const int nt   = wid & 7;
    const int lane = threadIdx.x & 63;

    const short* pa = (const short*)cnt + (size_t)(mt * 16 + (lane & 15)) * K + (lane >> 4) * 8;
    const short* pb = (const short*)bt  + (size_t)(nt * 16 + (lane & 15)) * K + (lane >> 4) * 8;

    f32x4 acc = {0.f, 0.f, 0.f, 0.f};
    #pragma unroll 8
    for (int kk = 0; kk < 52; ++kk) {
        short8 a = *(const short8*)(pa + kk * 32);
        short8 bv = *(const short8*)(pb + kk * 32);
        acc = __builtin_amdgcn_mfma_f32_16x16x32_bf16(a, bv, acc, 0, 0, 0);
    }

    // contribution: col n < 64 -> s^2 ; n >= 64 -> -sq
    const int n = nt * 16 + (lane & 15);
    #pragma unroll
    for (int r = 0; r < 4; ++r) {
        float v = acc[r];
        float c = (n < 64) ? v * v : -v;
        c += __shfl_xor(c, 1);
        c += __shfl_xor(c, 2);
        c += __shfl_xor(c, 4);
        c += __shfl_xor(c, 8);
        if ((lane & 15) == 0)
            atomicAdd(&pair[mt * 16 + (lane >> 4) * 4 + r], c);
    }

    // last-wave-per-mt fused epilogue
    __threadfence();
    unsigned int old = 0u;
    if (lane == 0) old = atomicAdd(&done[mt], 1u);
    old = __shfl(old, 0);
    if (old == 7u) {
        __threadfence();
        if (lane < 16) {
            const int row = mt * 16 + lane;
            const float p = atomicAdd(&pair[row], 0.f);   // coherent read
            float x = lin[row] + lin_b[0] + 0.5f * p;
            const float* dp = dense + (size_t)row * D;
            #pragma unroll
            for (int j = 0; j < D; ++j) x = fmaf(dp[j], lin_W[F + j], x);
            out[row] = 1.f / (1.f + expf(-x));
        }
    }
}

// ---------------------------------------------------------------------------
// Fallback (round-1 kernel) if ws is too small.
__global__ __launch_bounds__(256) void dfm_fallback(
    const int*   __restrict__ sparse,
    const float* __restrict__ dense,
    const float* __restrict__ lin_emb,
    const float* __restrict__ emb_tab,
    const float* __restrict__ lin_W,
    const float* __restrict__ lin_b,
    float*       __restrict__ out)
{
    const int lane = threadIdx.x & 63;
    const int wv   = threadIdx.x >> 6;
    const int b    = blockIdx.x * 4 + wv;
    if (b >= B) return;
    const int g = lane >> 4;
    const int t = lane & 15;
    const float4* emb4 = reinterpret_cast<const float4*>(emb_tab);
    float4 s  = make_float4(0.f, 0.f, 0.f, 0.f);
    float4 sq = make_float4(0.f, 0.f, 0.f, 0.f);
    float  lin = 0.f;
    const int sbase = b * SPARSE_W;
    for (int f = 0; f < F; ++f) {
        int idxreg = sparse[sbase + f * (C + 1) + lane];
        lin = fmaf(lin_W[f], lin_emb[f * C + idxreg], lin);
        const float4* rowbase = emb4 + (size_t)(f * C) * 16 + t;
        #pragma unroll
        for (int cc = 0; cc < 16; ++cc) {
            const int c   = g * 16 + cc;
            const int idx = __shfl(idxreg, c);
            float4 w = rowbase[idx * 16];
            s.x += w.x; s.y += w.y; s.z += w.z; s.w += w.w;
            sq.x = fmaf(w.x, w.x, sq.x);
            sq.y = fmaf(w.y, w.y, sq.y);
            sq.z = fmaf(w.z, w.z, sq.z);
            sq.w = fmaf(w.w, w.w, sq.w);
        }
    }
    if (lane < D) lin = fmaf(dense[b * D + lane], lin_W[F + lane], lin);
    #pragma unroll
    for (int m = 32; m >= 1; m >>= 1) lin += __shfl_xor(lin, m);
    #pragma unroll
    for (int m = 16; m <= 32; m <<= 1) {
        s.x += __shfl_xor(s.x, m); s.y += __shfl_xor(s.y, m);
        s.z += __shfl_xor(s.z, m); s.w += __shfl_xor(s.w, m);
    }
    float sql = sq.x + sq.y + sq.z + sq.w;
    #pragma unroll
    for (int m = 32; m >= 1; m >>= 1) sql += __shfl_xor(sql, m);
    float s2 = s.x * s.x + s.y * s.y + s.z * s.z + s.w * s.w;
    #pragma unroll
    for (int m = 8; m >= 1; m >>= 1) s2 += __shfl_xor(s2, m);
    if (lane == 0) {
        const float pair = 0.5f * (s2 - sql);
        const float x = lin + lin_b[0] + pair;
        out[b] = 1.f / (1.f + expf(-x));
    }
}

extern "C" void kernel_launch(void* const* d_in, const int* in_sizes, int n_in,
                              void* d_out, int out_size, void* d_ws, size_t ws_size,
                              hipStream_t stream) {
    const int*   sparse  = (const int*)  d_in[0];
    const float* dense   = (const float*)d_in[1];
    const float* lin_emb = (const float*)d_in[2];
    const float* emb_tab = (const float*)d_in[3];
    const float* lin_W   = (const float*)d_in[4];
    const float* lin_b   = (const float*)d_in[5];
    float* out = (float*)d_out;

    if (ws_size < WS_NEED) {
        dim3 grid((B + 3) / 4), block(256);
        hipLaunchKernelGGL(dfm_fallback, grid, block, 0, stream,
                           sparse, dense, lin_emb, emb_tab, lin_W, lin_b, out);
        return;
    }

    char* ws = (char*)d_ws;
    __hip_bfloat16* cnt = (__hip_bfloat16*)(ws + CNT_OFF);
    __hip_bfloat16* bt  = (__hip_bfloat16*)(ws + BT_OFF);
    float*          lin = (float*)(ws + LIN_OFF);
    float*          pr  = (float*)(ws + PAIR_OFF);
    unsigned int*   dn  = (unsigned int*)(ws + DONE_OFF);

    hipLaunchKernelGGL(hist_prep_kernel, dim3(B + F), dim3(256), 0, stream,
                       sparse, lin_emb, emb_tab, lin_W, cnt, bt, lin, pr, dn);
    hipLaunchKernelGGL(gemm_kernel, dim3(512), dim3(128), 0, stream,
                       cnt, bt, dense, lin_W, lin_b, lin, pr, dn, out);
}

// Round 6
// 33.550 us; speedup vs baseline: 2.3063x; 1.3060x over previous
//
#include <hip/hip_runtime.h>
#include <hip/hip_bf16.h>
#include <math.h>

// Problem constants
#define B 2048
#define F 26
#define C 64
#define E 64
#define D 13
#define SPARSE_W (F * (C + 1) - 1)   // 1689
#define K (F * C)                    // 1664
#define MT 4                         // samples per block (fused)
#define ROWW 836                     // dwords per LDS count row (3344 B)

typedef short short8 __attribute__((ext_vector_type(8)));
typedef float f32x4  __attribute__((ext_vector_type(4)));

// ws layout (bytes): bt bf16 [64][1664], tab float2 [1664]
#define BT_OFF  0
#define TAB_OFF ((size_t)64 * K * 2)            // 212,992
#define WS_NEED (TAB_OFF + (size_t)K * 8)       // 226,304

// ---------------------------------------------------------------------------
// Prep: 52 blocks, block handles feature f = blockIdx.x>>1, v-half = blockIdx.x&1.
//  bt[e][f*64+v] = bf16(emb[f,v,e])  (transposed, packed dword stores)
//  tab[f*64+v]   = (lin_W[f]*lin_emb[f,v],  sum_e emb[f,v,e]^2)
__global__ __launch_bounds__(256) void prep_kernel(
    const float* __restrict__ emb_tab,
    const float* __restrict__ lin_emb,
    const float* __restrict__ lin_W,
    __hip_bfloat16* __restrict__ bt,
    float2* __restrict__ tab)
{
    __shared__ float tile[32][65];
    const int f  = blockIdx.x >> 1;
    const int vh = (blockIdx.x & 1) * 32;    // v-half base
    const int tid = threadIdx.x;

    const float* src = emb_tab + (size_t)f * 4096 + (size_t)vh * 64;  // [v][e]
    for (int i = tid; i < 2048; i += 256)
        tile[i >> 6][i & 63] = src[i];
    __syncthreads();

    // bt stores: u = dword slot (v pair within half), e rows
    unsigned int* btw = (unsigned int*)bt;
    const int u  = tid & 15;          // v = vh + 2u, vh + 2u+1
    const int e0 = tid >> 4;          // 0..15
    #pragma unroll
    for (int it = 0; it < 4; ++it) {
        const int e = e0 + it * 16;   // 0..63
        float lo = tile[2 * u][e];
        float hi = tile[2 * u + 1][e];
        __hip_bfloat16 l16 = __float2bfloat16(lo);
        __hip_bfloat16 h16 = __float2bfloat16(hi);
        unsigned int dw = ((unsigned int)*(unsigned short*)&h16 << 16)
                        |  (unsigned int)*(unsigned short*)&l16;
        btw[(size_t)e * (K / 2) + f * 32 + vh / 2 + u] = dw;
    }

    // tab: threads 0..31 -> v = vh + tid
    if (tid < 32) {
        const int v = tid;
        float sq = 0.f;
        #pragma unroll
        for (int e = 0; e < 64; ++e) {
            const float x = tile[v][e];
            sq = fmaf(x, x, sq);
        }
        const int k = f * 64 + vh + v;
        tab[k] = make_float2(lin_W[f] * lin_emb[k], sq);
    }
}

// ---------------------------------------------------------------------------
// Fused: 512 blocks x 256 thr (4 waves). Wave w = sample b0+w.
//  phase H: private LDS u16 histogram + (lin, sqnorm) float2 gather
//  convert u16 -> bf16 in place
//  phase G: MFMA S = cnt(4x1664) @ bt^T(64x1664); epilogue sigmoid.
__global__ __launch_bounds__(256) void fused_kernel(
    const int*   __restrict__ sparse,
    const float* __restrict__ dense,
    const float* __restrict__ lin_W,
    const float* __restrict__ lin_b,
    const __hip_bfloat16* __restrict__ bt,
    const float2* __restrict__ tab,
    float* __restrict__ out)
{
    __shared__ unsigned int cnt[MT * ROWW];   // 13,376 B
    __shared__ float2 linsq[MT];
    __shared__ float  pair2[MT];

    const int tid  = threadIdx.x;
    const int lane = tid & 63;
    const int w    = tid >> 6;
    const int b0   = blockIdx.x * MT;

    for (int i = tid; i < MT * ROWW; i += 256) cnt[i] = 0u;
    if (tid < MT) pair2[tid] = 0.f;
    __syncthreads();

    // ---- phase H: wave w's sample
    const int* sp = sparse + (size_t)(b0 + w) * SPARSE_W;
    int vals[27];
    #pragma unroll
    for (int it = 0; it < 27; ++it) {
        const int p = lane + it * 64;
        vals[it] = (p < SPARSE_W) ? sp[p] : -1;
    }

    unsigned int* myrow = &cnt[w * ROWW];
    float2 acc = make_float2(0.f, 0.f);
    #pragma unroll
    for (int it = 0; it < 27; ++it) {
        const int p = lane + it * 64;
        if (vals[it] >= 0) {
            const int f = p / 65;
            const int c = p - f * 65;
            if (c < 64) {
                const int k = f * 64 + vals[it];
                atomicAdd(&myrow[k >> 1], 1u << (16 * (k & 1)));
                const float2 t = tab[k];
                acc.x += t.x;
                acc.y += t.y;
            }
        }
    }
    #pragma unroll
    for (int m = 32; m >= 1; m >>= 1) {
        acc.x += __shfl_xor(acc.x, m);
        acc.y += __shfl_xor(acc.y, m);
    }
    if (lane == 0) linsq[w] = acc;
    __syncthreads();

    // ---- convert u16 -> bf16 in place (ints <=64 exact under truncation)
    for (int i = tid; i < MT * ROWW; i += 256) {
        const unsigned int v = cnt[i];
        const float flo = (float)(v & 0xffffu);
        const float fhi = (float)(v >> 16);
        cnt[i] = (__float_as_uint(fhi) & 0xffff0000u) | (__float_as_uint(flo) >> 16);
    }
    __syncthreads();

    // ---- phase G: wave w -> cols [16w, 16w+16). A rows 0..3 live, 4..15 zero.
    const int  row  = lane & 15;
    const bool live = row < MT;
    const char*  pa = (const char*)cnt + (size_t)(row & (MT - 1)) * (ROWW * 4) + (lane >> 4) * 16;
    const short* pb = (const short*)bt + (size_t)(w * 16 + row) * K + (lane >> 4) * 8;

    const short8 zero8 = {0, 0, 0, 0, 0, 0, 0, 0};
    f32x4 acc4 = {0.f, 0.f, 0.f, 0.f};
    #pragma unroll 4
    for (int kk = 0; kk < 52; ++kk) {
        short8 at = *(const short8*)(pa + (size_t)kk * 64);
        short8 bv = *(const short8*)(pb + (size_t)kk * 32);
        short8 av = live ? at : zero8;
        acc4 = __builtin_amdgcn_mfma_f32_16x16x32_bf16(av, bv, acc4, 0, 0, 0);
    }

    // ---- epilogue: rows 4..15 are exactly 0 (zero A), so all lanes reduce.
    #pragma unroll
    for (int r = 0; r < MT; ++r) {
        float c = acc4[r] * acc4[r];
        c += __shfl_xor(c, 1);
        c += __shfl_xor(c, 2);
        c += __shfl_xor(c, 4);
        c += __shfl_xor(c, 8);
        // lane 0 holds sum over this wave's 16 cols for output row r
        if (lane == 0) atomicAdd(&pair2[r], c);
    }
    __syncthreads();

    if (tid < MT) {
        const int r = tid;
        const float2 ls = linsq[r];
        float x = ls.x + lin_b[0] + 0.5f * (pair2[r] - ls.y);
        const float* dp = dense + (size_t)(b0 + r) * D;
        #pragma unroll
        for (int j = 0; j < D; ++j) x = fmaf(dp[j], lin_W[F + j], x);
        out[b0 + r] = 1.f / (1.f + expf(-x));
    }
}

// ---------------------------------------------------------------------------
// Fallback (round-1 kernel) if ws is too small.
__global__ __launch_bounds__(256) void dfm_fallback(
    const int*   __restrict__ sparse,
    const float* __restrict__ dense,
    const float* __restrict__ lin_emb,
    const float* __restrict__ emb_tab,
    const float* __restrict__ lin_W,
    const float* __restrict__ lin_b,
    float*       __restrict__ out)
{
    const int lane = threadIdx.x & 63;
    const int wv   = threadIdx.x >> 6;
    const int b    = blockIdx.x * 4 + wv;
    if (b >= B) return;
    const int g = lane >> 4;
    const int t = lane & 15;
    const float4* emb4 = reinterpret_cast<const float4*>(emb_tab);
    float4 s  = make_float4(0.f, 0.f, 0.f, 0.f);
    float4 sq = make_float4(0.f, 0.f, 0.f, 0.f);
    float  lin = 0.f;
    const int sbase = b * SPARSE_W;
    for (int f = 0; f < F; ++f) {
        int idxreg = sparse[sbase + f * (C + 1) + lane];
        lin = fmaf(lin_W[f], lin_emb[f * C + idxreg], lin);
        const float4* rowbase = emb4 + (size_t)(f * C) * 16 + t;
        #pragma unroll
        for (int cc = 0; cc < 16; ++cc) {
            const int c   = g * 16 + cc;
            const int idx = __shfl(idxreg, c);
            float4 w = rowbase[idx * 16];
            s.x += w.x; s.y += w.y; s.z += w.z; s.w += w.w;
            sq.x = fmaf(w.x, w.x, sq.x);
            sq.y = fmaf(w.y, w.y, sq.y);
            sq.z = fmaf(w.z, w.z, sq.z);
            sq.w = fmaf(w.w, w.w, sq.w);
        }
    }
    if (lane < D) lin = fmaf(dense[b * D + lane], lin_W[F + lane], lin);
    #pragma unroll
    for (int m = 32; m >= 1; m >>= 1) lin += __shfl_xor(lin, m);
    #pragma unroll
    for (int m = 16; m <= 32; m <<= 1) {
        s.x += __shfl_xor(s.x, m); s.y += __shfl_xor(s.y, m);
        s.z += __shfl_xor(s.z, m); s.w += __shfl_xor(s.w, m);
    }
    float sql = sq.x + sq.y + sq.z + sq.w;
    #pragma unroll
    for (int m = 32; m >= 1; m >>= 1) sql += __shfl_xor(sql, m);
    float s2 = s.x * s.x + s.y * s.y + s.z * s.z + s.w * s.w;
    #pragma unroll
    for (int m = 8; m >= 1; m >>= 1) s2 += __shfl_xor(s2, m);
    if (lane == 0) {
        const float pair = 0.5f * (s2 - sql);
        const float x = lin + lin_b[0] + pair;
        out[b] = 1.f / (1.f + expf(-x));
    }
}

extern "C" void kernel_launch(void* const* d_in, const int* in_sizes, int n_in,
                              void* d_out, int out_size, void* d_ws, size_t ws_size,
                              hipStream_t stream) {
    const int*   sparse  = (const int*)  d_in[0];
    const float* dense   = (const float*)d_in[1];
    const float* lin_emb = (const float*)d_in[2];
    const float* emb_tab = (const float*)d_in[3];
    const float* lin_W   = (const float*)d_in[4];
    const float* lin_b   = (const float*)d_in[5];
    float* out = (float*)d_out;

    if (ws_size < WS_NEED) {
        dim3 grid((B + 3) / 4), block(256);
        hipLaunchKernelGGL(dfm_fallback, grid, block, 0, stream,
                           sparse, dense, lin_emb, emb_tab, lin_W, lin_b, out);
        return;
    }

    char* ws = (char*)d_ws;
    __hip_bfloat16* bt  = (__hip_bfloat16*)(ws + BT_OFF);
    float2*         tab = (float2*)(ws + TAB_OFF);

    hipLaunchKernelGGL(prep_kernel, dim3(2 * F), dim3(256), 0, stream,
                       emb_tab, lin_emb, lin_W, bt, tab);
    hipLaunchKernelGGL(fused_kernel, dim3(B / MT), dim3(256), 0, stream,
                       sparse, dense, lin_W, lin_b, bt, tab, out);
}

// Round 7
// 26.505 us; speedup vs baseline: 2.9193x; 1.2658x over previous
//
#include <hip/hip_runtime.h>
#include <hip/hip_bf16.h>
#include <math.h>

// Problem constants
#define B 2048
#define F 26
#define C 64
#define E 64
#define D 13
#define SPARSE_W (F * (C + 1) - 1)   // 1689
#define K (F * C)                    // 1664
#define KH (K / 2)                   // 832
#define MT 16                        // samples per fused block
#define ROWW 836                     // dwords per LDS count row (3344 B)
#define PREPB F                      // 26 prep blocks
#define FUSEB (B / MT)               // 128 fused blocks

typedef short short8 __attribute__((ext_vector_type(8)));
typedef float f32x4  __attribute__((ext_vector_type(4)));

// ws layout (bytes): bt bf16 [64][1664] | nrm f32 [1664] | flag u32
#define BT_OFF   0
#define NRM_OFF  ((size_t)64 * K * 2)           // 212,992
#define FLAG_OFF (NRM_OFF + (size_t)K * 4)      // 219,648
#define WS_NEED  (FLAG_OFF + 64)

// ---------------------------------------------------------------------------
// Single compute kernel.
//  bid < 26 : prep — bt[e][k]=bf16(emb[k,e]) (S-half only) + nrm[k]=sum_e emb^2
//             then atomicOr(flag, 1<<f) (release, agent scope).
//  bid >= 26: fused — LDS u16 histogram (overlaps prep) + linear gather,
//             u16->bf16, acquire-spin on flag, MFMA S-GEMM (N=64, waves =
//             n-tile x k-half), s^2 reduce + sq-dot vs nrm, sigmoid.
__global__ __launch_bounds__(512) void dfm_one(
    const int*   __restrict__ sparse,
    const float* __restrict__ dense,
    const float* __restrict__ lin_emb,
    const float* __restrict__ emb_tab,
    const float* __restrict__ lin_W,
    const float* __restrict__ lin_b,
    __hip_bfloat16* __restrict__ bt,
    float* __restrict__ nrm,
    unsigned int* __restrict__ flag,
    float* __restrict__ out)
{
    __shared__ union SM {
        struct {
            unsigned int cnt[MT * ROWW];   // 53,504 B
            float sbuf[2][MT][64];         //  8,192 B
            float lin[MT];
            float s2[MT];
            float sq[MT];
            int   ready;
        } f;
        struct { float tile[64][65]; } p;  // 16,640 B
    } sm;

    const int tid  = threadIdx.x;
    const int lane = tid & 63;
    const int w    = tid >> 6;
    const int bid  = blockIdx.x;

    if (bid < PREPB) {
        // ---------------- prep path ----------------
        const int f = bid;
        const float* src = emb_tab + (size_t)f * 4096;   // [v][e]
        for (int i = tid; i < 4096; i += 512)
            sm.p.tile[i >> 6][i & 63] = src[i];
        __syncthreads();

        unsigned int* btw = (unsigned int*)bt;
        #pragma unroll
        for (int it = 0; it < 4; ++it) {
            const int d = tid + it * 512;   // 0..2047
            const int e = d >> 5;           // 0..63
            const int u = d & 31;           // v pair
            float lo = sm.p.tile[2 * u][e];
            float hi = sm.p.tile[2 * u + 1][e];
            __hip_bfloat16 l16 = __float2bfloat16(lo);
            __hip_bfloat16 h16 = __float2bfloat16(hi);
            btw[(size_t)e * (K / 2) + f * 32 + u] =
                ((unsigned int)*(unsigned short*)&h16 << 16)
              |  (unsigned int)*(unsigned short*)&l16;
        }
        if (tid < 64) {
            float s = 0.f;
            #pragma unroll
            for (int e = 0; e < 64; ++e) {
                const float x = sm.p.tile[tid][e];
                s = fmaf(x, x, s);
            }
            nrm[f * 64 + tid] = s;
        }
        __syncthreads();   // drains all vmem stores (compiler waits vmcnt(0))
        if (tid == 0)
            __hip_atomic_fetch_or(flag, 1u << f, __ATOMIC_RELEASE,
                                  __HIP_MEMORY_SCOPE_AGENT);
        return;
    }

    // ---------------- fused path ----------------
    const int b0 = (bid - PREPB) * MT;

    for (int i = tid; i < MT * ROWW; i += 512) sm.f.cnt[i] = 0u;
    __syncthreads();

    // phase H: wave w owns sample rows w and w+8
    const int r0 = w, r1 = w + 8;
    const int* sp0 = sparse + (size_t)(b0 + r0) * SPARSE_W + lane;
    const int* sp1 = sparse + (size_t)(b0 + r1) * SPARSE_W + lane;
    int idx0[F], idx1[F];
    #pragma unroll
    for (int f = 0; f < F; ++f) idx0[f] = sp0[f * (C + 1)];
    #pragma unroll
    for (int f = 0; f < F; ++f) idx1[f] = sp1[f * (C + 1)];

    float lin0 = 0.f, lin1 = 0.f;
    #pragma unroll
    for (int f = 0; f < F; ++f) {
        const int k0 = f * 64 + idx0[f];
        const int k1 = f * 64 + idx1[f];
        atomicAdd(&sm.f.cnt[r0 * ROWW + (k0 >> 1)], 1u << (16 * (k0 & 1)));
        atomicAdd(&sm.f.cnt[r1 * ROWW + (k1 >> 1)], 1u << (16 * (k1 & 1)));
        lin0 = fmaf(lin_W[f], lin_emb[k0], lin0);
        lin1 = fmaf(lin_W[f], lin_emb[k1], lin1);
    }
    #pragma unroll
    for (int m = 32; m >= 1; m >>= 1) {
        lin0 += __shfl_xor(lin0, m);
        lin1 += __shfl_xor(lin1, m);
    }
    if (lane == 0) { sm.f.lin[r0] = lin0; sm.f.lin[r1] = lin1; }
    __syncthreads();

    // u16 -> bf16 in place (ints <=64 exact under truncation)
    {
        const int row = tid >> 5;
        const int cl  = tid & 31;
        unsigned int* rp = &sm.f.cnt[row * ROWW];
        #pragma unroll
        for (int it = 0; it < 26; ++it) {
            const int j = cl + it * 32;
            const unsigned int v = rp[j];
            const float flo = (float)(v & 0xffffu);
            const float fhi = (float)(v >> 16);
            rp[j] = (__float_as_uint(fhi) & 0xffff0000u) | (__float_as_uint(flo) >> 16);
        }
    }

    // wait for prep (expected ~0 spin: prep finishes well before hist)
    if (tid == 0) {
        while ((__hip_atomic_load(flag, __ATOMIC_ACQUIRE,
                                  __HIP_MEMORY_SCOPE_AGENT) & 0x3FFFFFFu)
               != 0x3FFFFFFu)
            __builtin_amdgcn_s_sleep(16);
        sm.f.ready = 1;
    }
    __syncthreads();

    // phase G: wave w -> n-tile (w&3), k-half (w>>2). A: LDS cnt; B: bt (L2).
    const int nt = w & 3, kh = w >> 2;
    const char*  pa = (const char*)sm.f.cnt + (size_t)(lane & 15) * (ROWW * 4)
                    + kh * (KH * 2) + (lane >> 4) * 16;
    const short* pb = (const short*)bt + (size_t)(nt * 16 + (lane & 15)) * K
                    + kh * KH + (lane >> 4) * 8;
    f32x4 acc = {0.f, 0.f, 0.f, 0.f};
    #pragma unroll 13
    for (int kk = 0; kk < 26; ++kk) {
        short8 a  = *(const short8*)(pa + (size_t)kk * 64);
        short8 bv = *(const short8*)(pb + (size_t)kk * 32);
        acc = __builtin_amdgcn_mfma_f32_16x16x32_bf16(a, bv, acc, 0, 0, 0);
    }
    {
        const int col = nt * 16 + (lane & 15);
        const int rb  = (lane >> 4) * 4;
        #pragma unroll
        for (int r = 0; r < 4; ++r) sm.f.sbuf[kh][rb + r][col] = acc[r];
    }
    __syncthreads();

    // epilogue: s^2 reduce (combine k-halves first) + sq-dot vs nrm
    {
        const int row = tid >> 5;
        const int cl  = tid & 31;
        const float a0 = sm.f.sbuf[0][row][2 * cl]     + sm.f.sbuf[1][row][2 * cl];
        const float a1 = sm.f.sbuf[0][row][2 * cl + 1] + sm.f.sbuf[1][row][2 * cl + 1];
        float s2v = a0 * a0 + a1 * a1;
        float sqv = 0.f;
        const unsigned int* crow = &sm.f.cnt[row * ROWW];
        const float2* n2 = (const float2*)nrm;
        #pragma unroll
        for (int i = 0; i < 26; ++i) {
            const int j = cl + i * 32;
            const unsigned int dw = crow[j];
            const float lo = __uint_as_float(dw << 16);
            const float hi = __uint_as_float(dw & 0xffff0000u);
            const float2 nn = n2[j];
            sqv = fmaf(lo, nn.x, sqv);
            sqv = fmaf(hi, nn.y, sqv);
        }
        #pragma unroll
        for (int m = 16; m >= 1; m >>= 1) {
            s2v += __shfl_xor(s2v, m);
            sqv += __shfl_xor(sqv, m);
        }
        if (cl == 0) { sm.f.s2[row] = s2v; sm.f.sq[row] = sqv; }
    }
    __syncthreads();

    if (tid < MT) {
        float x = sm.f.lin[tid] + lin_b[0] + 0.5f * (sm.f.s2[tid] - sm.f.sq[tid]);
        const float* dp = dense + (size_t)(b0 + tid) * D;
        #pragma unroll
        for (int j = 0; j < D; ++j) x = fmaf(dp[j], lin_W[F + j], x);
        out[b0 + tid] = 1.f / (1.f + expf(-x));
    }
}

// ---------------------------------------------------------------------------
// Fallback (round-1 kernel) if ws is too small.
__global__ __launch_bounds__(256) void dfm_fallback(
    const int*   __restrict__ sparse,
    const float* __restrict__ dense,
    const float* __restrict__ lin_emb,
    const float* __restrict__ emb_tab,
    const float* __restrict__ lin_W,
    const float* __restrict__ lin_b,
    float*       __restrict__ out)
{
    const int lane = threadIdx.x & 63;
    const int wv   = threadIdx.x >> 6;
    const int b    = blockIdx.x * 4 + wv;
    if (b >= B) return;
    const int g = lane >> 4;
    const int t = lane & 15;
    const float4* emb4 = reinterpret_cast<const float4*>(emb_tab);
    float4 s  = make_float4(0.f, 0.f, 0.f, 0.f);
    float4 sq = make_float4(0.f, 0.f, 0.f, 0.f);
    float  lin = 0.f;
    const int sbase = b * SPARSE_W;
    for (int f = 0; f < F; ++f) {
        int idxreg = sparse[sbase + f * (C + 1) + lane];
        lin = fmaf(lin_W[f], lin_emb[f * C + idxreg], lin);
        const float4* rowbase = emb4 + (size_t)(f * C) * 16 + t;
        #pragma unroll
        for (int cc = 0; cc < 16; ++cc) {
            const int c   = g * 16 + cc;
            const int idx = __shfl(idxreg, c);
            float4 w = rowbase[idx * 16];
            s.x += w.x; s.y += w.y; s.z += w.z; s.w += w.w;
            sq.x = fmaf(w.x, w.x, sq.x);
            sq.y = fmaf(w.y, w.y, sq.y);
            sq.z = fmaf(w.z, w.z, sq.z);
            sq.w = fmaf(w.w, w.w, sq.w);
        }
    }
    if (lane < D) lin = fmaf(dense[b * D + lane], lin_W[F + lane], lin);
    #pragma unroll
    for (int m = 32; m >= 1; m >>= 1) lin += __shfl_xor(lin, m);
    #pragma unroll
    for (int m = 16; m <= 32; m <<= 1) {
        s.x += __shfl_xor(s.x, m); s.y += __shfl_xor(s.y, m);
        s.z += __shfl_xor(s.z, m); s.w += __shfl_xor(s.w, m);
    }
    float sql = sq.x + sq.y + sq.z + sq.w;
    #pragma unroll
    for (int m = 32; m >= 1; m >>= 1) sql += __shfl_xor(sql, m);
    float s2 = s.x * s.x + s.y * s.y + s.z * s.z + s.w * s.w;
    #pragma unroll
    for (int m = 8; m >= 1; m >>= 1) s2 += __shfl_xor(s2, m);
    if (lane == 0) {
        const float pair = 0.5f * (s2 - sql);
        const float x = lin + lin_b[0] + pair;
        out[b] = 1.f / (1.f + expf(-x));
    }
}

extern "C" void kernel_launch(void* const* d_in, const int* in_sizes, int n_in,
                              void* d_out, int out_size, void* d_ws, size_t ws_size,
                              hipStream_t stream) {
    const int*   sparse  = (const int*)  d_in[0];
    const float* dense   = (const float*)d_in[1];
    const float* lin_emb = (const float*)d_in[2];
    const float* emb_tab = (const float*)d_in[3];
    const float* lin_W   = (const float*)d_in[4];
    const float* lin_b   = (const float*)d_in[5];
    float* out = (float*)d_out;

    if (ws_size < WS_NEED) {
        dim3 grid((B + 3) / 4), block(256);
        hipLaunchKernelGGL(dfm_fallback, grid, block, 0, stream,
                           sparse, dense, lin_emb, emb_tab, lin_W, lin_b, out);
        return;
    }

    char* ws = (char*)d_ws;
    __hip_bfloat16* bt   = (__hip_bfloat16*)(ws + BT_OFF);
    float*          nrm  = (float*)(ws + NRM_OFF);
    unsigned int*   flag = (unsigned int*)(ws + FLAG_OFF);

    hipMemsetAsync(flag, 0, sizeof(unsigned int), stream);
    hipLaunchKernelGGL(dfm_one, dim3(PREPB + FUSEB), dim3(512), 0, stream,
                       sparse, dense, lin_emb, emb_tab, lin_W, lin_b,
                       bt, nrm, flag, out);
}